// Round 3
// baseline (1029.073 us; speedup 1.0000x reference)
//
#include <hip/hip_runtime.h>
#include <hip/hip_bf16.h>
#include <math.h>

#define IN_CH 128
#define HID 64
#define OUT_CH 40

typedef const __hip_bfloat16* bf16p;

// ---- flag detection: flags[0]=1 if float tensors are f32, flags[1]=1 if indices are int64
__global__ void k_detect(const void* x, const void* ei, int* flags) {
    __shared__ int s_f32, s_hi;
    if (threadIdx.x == 0) { s_f32 = 0; s_hi = 0; }
    __syncthreads();
    const __hip_bfloat16* xb = (const __hip_bfloat16*)x;
    const int* ii = (const int*)ei;
    int lf = 0, lh = 0;
    for (int i = threadIdx.x; i < 4096; i += blockDim.x) {
        float f = __bfloat162float(xb[i]);
        if (!(fabsf(f) <= 1e4f)) lf = 1;       // huge/NaN -> buffer is really f32
        lh |= ii[2 * i + 1];                    // int64 high words are all zero
    }
    if (lf) atomicOr(&s_f32, 1);
    if (lh) atomicOr(&s_hi, 1);
    __syncthreads();
    if (threadIdx.x == 0) { flags[0] = s_f32 ? 1 : 0; flags[1] = (s_hi == 0) ? 1 : 0; }
}

// ---- convert weights/biases to f32: wf = [W1f 8192 | b1f 64 | W2f 2560 | b2f 40]
__global__ void k_convw(const void* W1, const void* b1, const void* W2, const void* b2,
                        const int* flags, float* wf) {
    int i = blockIdx.x * blockDim.x + threadIdx.x;
    if (i >= 10856) return;
    const void* src; int off;
    if (i < 8192)       { src = W1; off = i; }
    else if (i < 8256)  { src = b1; off = i - 8192; }
    else if (i < 10816) { src = W2; off = i - 8256; }
    else                { src = b2; off = i - 10816; }
    float v;
    if (flags[0]) v = ((const float*)src)[off];
    else          v = __bfloat162float(((bf16p)src)[off]);
    wf[i] = v;
}

// ---- degree over col (self-loop becomes +1 in k_dinv)
__global__ void k_deg(const int* ei, const int* flags, float* deg, int E) {
    int e = blockIdx.x * blockDim.x + threadIdx.x;
    if (e >= E) return;
    int c;
    if (flags[1]) c = ei[2 * (E + e)];
    else          c = ei[E + e];
    atomicAdd(&deg[c], 1.0f);
}

__global__ void k_dinv(const float* deg, float* dinv, int N) {
    int i = blockIdx.x * blockDim.x + threadIdx.x;
    if (i >= N) return;
    dinv[i] = rsqrtf(deg[i] + 1.0f);
}

// ---- GEMM1: h1[n][c] = sum_k x[n][k]*W1[k][c]; W1 in LDS; one wave per node; f32 store
__global__ __launch_bounds__(256) void k_gemm1(const void* x, const float* W1f,
                                               float* h1, const int* flags, int N) {
    __shared__ float w[IN_CH * HID];
    for (int i = threadIdx.x; i < IN_CH * HID; i += 256) w[i] = W1f[i];
    __syncthreads();
    const int isF32 = flags[0];
    const int c = threadIdx.x & 63;
    const int q = threadIdx.x >> 6;
    for (int n = blockIdx.x * 4 + q; n < N; n += gridDim.x * 4) {
        float acc = 0.f;
        if (isF32) {
            const float* xr = (const float*)x + (size_t)n * IN_CH;
            #pragma unroll 8
            for (int k = 0; k < IN_CH; ++k) acc += xr[k] * w[k * HID + c];
        } else {
            bf16p xr = (bf16p)x + (size_t)n * IN_CH;
            #pragma unroll 8
            for (int k = 0; k < IN_CH; ++k) acc += __bfloat162float(xr[k]) * w[k * HID + c];
        }
        h1[(size_t)n * HID + c] = acc;
    }
}

// ---- Aggregation 1: one thread per (edge, channel of 64); wave-uniform edge
__global__ void k_agg1(const int* ei, const int* flags, const float* dinv,
                       const float* h1, float* agg1, int E, int total) {
    int idx = blockIdx.x * blockDim.x + threadIdx.x;
    if (idx >= total) return;
    int e = idx >> 6, c = idx & 63;
    int r, cl;
    if (flags[1]) { r = ei[2 * e]; cl = ei[2 * (E + e)]; }
    else          { r = ei[e];     cl = ei[E + e]; }
    float nrm = dinv[r] * dinv[cl];
    atomicAdd(&agg1[(size_t)cl * HID + c], h1[(size_t)r * HID + c] * nrm);
}

// ---- epilogue 1: self-loop + bias + ReLU, in place (f32)
__global__ void k_relu(float* agg1, const float* h1, const float* dinv,
                       const float* b1f, int total) {
    int idx = blockIdx.x * blockDim.x + threadIdx.x;
    if (idx >= total) return;
    int n = idx >> 6, c = idx & 63;
    float d = dinv[n];
    float v = agg1[idx] + h1[idx] * d * d + b1f[c];
    agg1[idx] = fmaxf(v, 0.f);
}

// ---- GEMM2: h2[n][c] = sum_k g[n][k]*W2[k][c]; f32 store
__global__ void k_gemm2(const float* g, const float* W2f, float* h2, int total) {
    int idx = blockIdx.x * blockDim.x + threadIdx.x;
    if (idx >= total) return;
    unsigned u = (unsigned)idx;
    unsigned n = u / 40u;
    unsigned c = u - n * 40u;
    const float* a = g + (size_t)n * HID;
    float acc = 0.f;
    #pragma unroll
    for (int k = 0; k < HID; ++k) acc += a[k] * W2f[k * OUT_CH + c];
    h2[idx] = acc;
}

// ---- Aggregation 2: one thread per (edge, channel of 40)
__global__ void k_agg2(const int* ei, const int* flags, const float* dinv,
                       const float* h2, float* agg2, int E, int total) {
    int idx = blockIdx.x * blockDim.x + threadIdx.x;
    if (idx >= total) return;
    unsigned u = (unsigned)idx;
    unsigned e = u / 40u;
    unsigned c = u - e * 40u;
    int r, cl;
    if (flags[1]) { r = ei[2 * e]; cl = ei[2 * (E + e)]; }
    else          { r = ei[e];     cl = ei[E + e]; }
    float nrm = dinv[r] * dinv[cl];
    atomicAdd(&agg2[(size_t)cl * OUT_CH + c], h2[(size_t)r * OUT_CH + c] * nrm);
}

// ---- final: self-loop + bias, write FLOAT32 output (reference output dtype)
__global__ void k_final(const float* agg2, const float* h2, const float* dinv,
                        const float* b2f, float* out, int total) {
    int idx = blockIdx.x * blockDim.x + threadIdx.x;
    if (idx >= total) return;
    unsigned u = (unsigned)idx;
    unsigned n = u / 40u;
    unsigned c = u - n * 40u;
    float d = dinv[n];
    out[idx] = agg2[idx] + h2[idx] * d * d + b2f[c];
}

extern "C" void kernel_launch(void* const* d_in, const int* in_sizes, int n_in,
                              void* d_out, int out_size, void* d_ws, size_t ws_size,
                              hipStream_t stream) {
    const void* x  = d_in[0];
    const void* ei = d_in[1];
    const void* W1 = d_in[2];
    const void* b1 = d_in[3];
    const void* W2 = d_in[4];
    const void* b2 = d_in[5];
    const int N = in_sizes[0] / IN_CH;   // 100000
    const int E = in_sizes[1] / 2;       // 1600000
    const int* eii = (const int*)ei;

    // ---- workspace layout (float units), small stuff first. Peak ≈ 52.3 MB.
    float* ws = (float*)d_ws;
    int*   flags = (int*)ws;                       // [0,16)
    float* deg   = ws + 16;                        // N
    float* dinv  = ws + 16 + N;                    // N
    float* wf    = ws + 16 + 2 * N;                // 10880 floats of weights
    float* h1    = ws + 262144;                    // 6.4M f32 (h1; later h2 in first 4M)
    float* agg   = h1 + (size_t)N * HID;           // 6.4M f32 (agg1/g; later agg2 in first 4M)
    float* h2    = h1;                             // alias: h1 dead after k_relu

    hipMemsetAsync(deg, 0, (size_t)N * sizeof(float), stream);
    hipMemsetAsync(agg, 0, (size_t)N * HID * sizeof(float), stream);

    k_detect<<<1, 256, 0, stream>>>(x, ei, flags);
    k_convw<<<(10856 + 255) / 256, 256, 0, stream>>>(W1, b1, W2, b2, flags, wf);
    k_deg<<<(E + 255) / 256, 256, 0, stream>>>(eii, flags, deg, E);
    k_dinv<<<(N + 255) / 256, 256, 0, stream>>>(deg, dinv, N);

    k_gemm1<<<4096, 256, 0, stream>>>(x, wf, h1, flags, N);

    int t1 = E * HID;      // 102,400,000
    k_agg1<<<(t1 + 255) / 256, 256, 0, stream>>>(eii, flags, dinv, h1, agg, E, t1);

    int tr = N * HID;      // 6,400,000
    k_relu<<<(tr + 255) / 256, 256, 0, stream>>>(agg, h1, dinv, wf + 8192, tr);

    int tg2 = N * OUT_CH;  // 4,000,000
    k_gemm2<<<(tg2 + 255) / 256, 256, 0, stream>>>(agg, wf + 8256, h2, tg2);

    // g (agg region) dead after gemm2 — reuse first 4M floats for agg2
    hipMemsetAsync(agg, 0, (size_t)N * OUT_CH * sizeof(float), stream);

    int t2 = E * OUT_CH;   // 64,000,000
    k_agg2<<<(t2 + 255) / 256, 256, 0, stream>>>(eii, flags, dinv, h2, agg, E, t2);

    k_final<<<(tg2 + 255) / 256, 256, 0, stream>>>(agg, h2, dinv, wf + 10816,
                                                   (float*)d_out, tg2);
}

// Round 5
// 578.993 us; speedup vs baseline: 1.7774x; 1.7774x over previous
//
#include <hip/hip_runtime.h>
#include <hip/hip_bf16.h>
#include <math.h>

#define IN_CH 128
#define HID 64
#define OUT_CH 40

typedef const __hip_bfloat16* bf16p;

// ---- flag detection: flags[0]=1 if float tensors are f32, flags[1]=1 if indices are int64
__global__ void k_detect(const void* x, const void* ei, int* flags) {
    __shared__ int s_f32, s_hi;
    if (threadIdx.x == 0) { s_f32 = 0; s_hi = 0; }
    __syncthreads();
    const __hip_bfloat16* xb = (const __hip_bfloat16*)x;
    const int* ii = (const int*)ei;
    int lf = 0, lh = 0;
    for (int i = threadIdx.x; i < 4096; i += blockDim.x) {
        float f = __bfloat162float(xb[i]);
        if (!(fabsf(f) <= 1e4f)) lf = 1;       // huge/NaN -> buffer is really f32
        lh |= ii[2 * i + 1];                    // int64 high words are all zero
    }
    if (lf) atomicOr(&s_f32, 1);
    if (lh) atomicOr(&s_hi, 1);
    __syncthreads();
    if (threadIdx.x == 0) { flags[0] = s_f32 ? 1 : 0; flags[1] = (s_hi == 0) ? 1 : 0; }
}

// ---- convert weights/biases to f32: wf = [W1f 8192 | b1f 64 | W2f 2560 | b2f 40]
__global__ void k_convw(const void* W1, const void* b1, const void* W2, const void* b2,
                        const int* flags, float* wf) {
    int i = blockIdx.x * blockDim.x + threadIdx.x;
    if (i >= 10856) return;
    const void* src; int off;
    if (i < 8192)       { src = W1; off = i; }
    else if (i < 8256)  { src = b1; off = i - 8192; }
    else if (i < 10816) { src = W2; off = i - 8256; }
    else                { src = b2; off = i - 10816; }
    float v;
    if (flags[0]) v = ((const float*)src)[off];
    else          v = __bfloat162float(((bf16p)src)[off]);
    wf[i] = v;
}

// ---- in-degree histogram over col (int)
__global__ void k_deg(const int* ei, const int* flags, int* deg, int E) {
    int e = blockIdx.x * blockDim.x + threadIdx.x;
    if (e >= E) return;
    int c;
    if (flags[1]) c = ei[2 * (E + e)];
    else          c = ei[E + e];
    atomicAdd(&deg[c], 1);
}

__global__ void k_dinv(const int* deg, float* dinv, int N) {
    int i = blockIdx.x * blockDim.x + threadIdx.x;
    if (i >= N) return;
    dinv[i] = rsqrtf((float)deg[i] + 1.0f);   // +1 = self-loop
}

// ---- exclusive scan over deg -> rowstart (3 kernels)
__global__ void k_blocksum(const int* deg, int* bsum, int N) {
    __shared__ int s[256];
    int i = blockIdx.x * 256 + threadIdx.x;
    s[threadIdx.x] = (i < N) ? deg[i] : 0;
    __syncthreads();
    for (int off = 128; off > 0; off >>= 1) {
        if (threadIdx.x < off) s[threadIdx.x] += s[threadIdx.x + off];
        __syncthreads();
    }
    if (threadIdx.x == 0) bsum[blockIdx.x] = s[0];
}

__global__ void k_scanbsum(int* bsum, int NB) {
    __shared__ int s[1024];
    __shared__ int carry_s;
    if (threadIdx.x == 0) carry_s = 0;
    __syncthreads();
    for (int base = 0; base < NB; base += 1024) {
        int i = base + threadIdx.x;
        int v = (i < NB) ? bsum[i] : 0;
        s[threadIdx.x] = v;
        __syncthreads();
        for (int off = 1; off < 1024; off <<= 1) {
            int t = (threadIdx.x >= off) ? s[threadIdx.x - off] : 0;
            __syncthreads();
            s[threadIdx.x] += t;
            __syncthreads();
        }
        int total = s[1023];
        int excl = s[threadIdx.x] - v + carry_s;
        if (i < NB) bsum[i] = excl;
        __syncthreads();
        if (threadIdx.x == 0) carry_s += total;
        __syncthreads();
    }
}

__global__ void k_scanfinal(const int* deg, const int* boff, int* rowstart, int N) {
    __shared__ int s[256];
    int i = blockIdx.x * 256 + threadIdx.x;
    int v = (i < N) ? deg[i] : 0;
    s[threadIdx.x] = v;
    __syncthreads();
    for (int off = 1; off < 256; off <<= 1) {
        int t = (threadIdx.x >= off) ? s[threadIdx.x - off] : 0;
        __syncthreads();
        s[threadIdx.x] += t;
        __syncthreads();
    }
    if (i < N) rowstart[i] = boff[blockIdx.x] + s[threadIdx.x] - v;
    if (i == N - 1) rowstart[N] = boff[blockIdx.x] + s[threadIdx.x];
}

// ---- bucket-scatter edges into CSR (row only; norm recomputed on the fly)
__global__ void k_scatter(const int* ei, const int* flags, const int* rowstart,
                          int* fill, int* erow, int E) {
    int e = blockIdx.x * blockDim.x + threadIdx.x;
    if (e >= E) return;
    int r, c;
    if (flags[1]) { r = ei[2 * e]; c = ei[2 * (E + e)]; }
    else          { r = ei[e];     c = ei[E + e]; }
    int pos = rowstart[c] + atomicAdd(&fill[c], 1);
    erow[pos] = r;
}

// ---- GEMM1: h1[n][c] = sum_k x[n][k]*W1[k][c]; W1 in LDS; one wave per node
__global__ __launch_bounds__(256) void k_gemm1(const void* x, const float* W1f,
                                               float* h1, const int* flags, int N) {
    __shared__ float w[IN_CH * HID];
    for (int i = threadIdx.x; i < IN_CH * HID; i += 256) w[i] = W1f[i];
    __syncthreads();
    const int isF32 = flags[0];
    const int c = threadIdx.x & 63;
    const int q = threadIdx.x >> 6;
    for (int n = blockIdx.x * 4 + q; n < N; n += gridDim.x * 4) {
        float acc = 0.f;
        if (isF32) {
            const float* xr = (const float*)x + (size_t)n * IN_CH;
            #pragma unroll 8
            for (int k = 0; k < IN_CH; ++k) acc += xr[k] * w[k * HID + c];
        } else {
            bf16p xr = (bf16p)x + (size_t)n * IN_CH;
            #pragma unroll 8
            for (int k = 0; k < IN_CH; ++k) acc += __bfloat162float(xr[k]) * w[k * HID + c];
        }
        h1[(size_t)n * HID + c] = acc;
    }
}

// ---- Fused aggregation1 (+self-loop+bias+ReLU) AND GEMM2: one wave per node.
//      Wave computes g[64] in registers (lane=channel), round-trips through a
//      per-wave LDS slice, then computes h2[n][0..39] in lanes 0..39.
__global__ __launch_bounds__(256) void k_agg1gemm2(const int* rowstart, const int* erow,
        const float* h1, const float* dinv, const float* b1f, const float* w2f,
        float* h2, int N) {
    __shared__ float w2[HID * OUT_CH];   // 2560 floats
    __shared__ float sg[256];            // per-wave g slices
    for (int i = threadIdx.x; i < HID * OUT_CH; i += 256) w2[i] = w2f[i];
    __syncthreads();

    int w = (blockIdx.x * 256 + threadIdx.x) >> 6;
    int c = threadIdx.x & 63;
    bool act = (w < N);
    float g = 0.f;
    if (act) {
        int s0 = __builtin_amdgcn_readfirstlane(rowstart[w]);
        int s1 = __builtin_amdgcn_readfirstlane(rowstart[w + 1]);
        float d = dinv[w];
        float acc = h1[(size_t)w * HID + c] * d * d + b1f[c];
        int i = s0;
        for (; i + 1 < s1; i += 2) {
            int r0 = erow[i];     int r1 = erow[i + 1];
            float n0 = dinv[r0] * d;
            float n1 = dinv[r1] * d;
            float v0 = h1[(size_t)r0 * HID + c];
            float v1 = h1[(size_t)r1 * HID + c];
            acc += v0 * n0 + v1 * n1;
        }
        if (i < s1) { int r = erow[i]; acc += h1[(size_t)r * HID + c] * (dinv[r] * d); }
        g = fmaxf(acc, 0.f);
    }
    sg[threadIdx.x] = g;
    __syncthreads();
    if (act && c < OUT_CH) {
        const float* gs = sg + (threadIdx.x & 192);   // this wave's 64-slice
        float acc2 = 0.f;
        #pragma unroll
        for (int k = 0; k < HID; ++k) acc2 += gs[k] * w2[k * OUT_CH + c];
        h2[(size_t)w * OUT_CH + c] = acc2;
    }
}

// ---- Aggregation 2 (CSR): one wave per node, lanes 0..39 = channels; fused final -> d_out
__global__ __launch_bounds__(256) void k_agg2_csr(const int* rowstart, const int* erow,
        const float* h2, const float* dinv, const float* b2f, float* out, int N) {
    int w = (blockIdx.x * 256 + threadIdx.x) >> 6;
    int c = threadIdx.x & 63;
    if (w >= N) return;
    int s0 = __builtin_amdgcn_readfirstlane(rowstart[w]);
    int s1 = __builtin_amdgcn_readfirstlane(rowstart[w + 1]);
    float d = dinv[w];
    float acc = 0.f;
    if (c < OUT_CH) acc = h2[(size_t)w * OUT_CH + c] * d * d + b2f[c];
    int i = s0;
    for (; i + 1 < s1; i += 2) {
        int r0 = erow[i];     int r1 = erow[i + 1];
        float n0 = dinv[r0] * d;
        float n1 = dinv[r1] * d;
        if (c < OUT_CH) {
            float v0 = h2[(size_t)r0 * OUT_CH + c];
            float v1 = h2[(size_t)r1 * OUT_CH + c];
            acc += v0 * n0 + v1 * n1;
        }
    }
    if (i < s1 && c < OUT_CH) {
        int r = erow[i];
        acc += h2[(size_t)r * OUT_CH + c] * (dinv[r] * d);
    }
    if (c < OUT_CH) out[(size_t)w * OUT_CH + c] = acc;
}

extern "C" void kernel_launch(void* const* d_in, const int* in_sizes, int n_in,
                              void* d_out, int out_size, void* d_ws, size_t ws_size,
                              hipStream_t stream) {
    const void* x  = d_in[0];
    const void* ei = d_in[1];
    const void* W1 = d_in[2];
    const void* b1 = d_in[3];
    const void* W2 = d_in[4];
    const void* b2 = d_in[5];
    const int N = in_sizes[0] / IN_CH;   // 100000
    const int E = in_sizes[1] / 2;       // 1600000
    const int* eii = (const int*)ei;
    const int NB = (N + 255) / 256;

    // ---- workspace layout (4-byte units). Peak ≈ 47.4 MiB (R3's proven-safe was 49.8).
    float* ws = (float*)d_ws;
    size_t off = 16;
    int*   flags    = (int*)ws;
    int*   deg      = (int*)ws + off;            off += N;
    int*   fill     = (int*)ws + off;            off += N;   // contiguous with deg: one memset
    float* dinv     = ws + off;                  off += N;
    float* wf       = ws + off;                  off += 10880;
    int*   bsum     = (int*)ws + off;            off += NB + 16;
    int*   rowstart = (int*)ws + off;            off += N + 1;
    off = (off + 255) & ~(size_t)255;
    int*   erow     = (int*)ws + off;            off += E;
    float* h1       = ws + off;                  off += (size_t)N * HID;
    float* h2       = ws + off;                  off += (size_t)N * OUT_CH;

    hipMemsetAsync(deg, 0, (size_t)2 * N * sizeof(int), stream);  // deg + fill

    k_detect<<<1, 256, 0, stream>>>(x, ei, flags);
    k_convw<<<(10856 + 255) / 256, 256, 0, stream>>>(W1, b1, W2, b2, flags, wf);
    k_deg<<<(E + 255) / 256, 256, 0, stream>>>(eii, flags, deg, E);
    k_dinv<<<(N + 255) / 256, 256, 0, stream>>>(deg, dinv, N);

    k_blocksum<<<NB, 256, 0, stream>>>(deg, bsum, N);
    k_scanbsum<<<1, 1024, 0, stream>>>(bsum, NB);
    k_scanfinal<<<NB, 256, 0, stream>>>(deg, bsum, rowstart, N);
    k_scatter<<<(E + 255) / 256, 256, 0, stream>>>(eii, flags, rowstart, fill, erow, E);

    k_gemm1<<<4096, 256, 0, stream>>>(x, wf, h1, flags, N);

    int nodeBlocks = (N * 64 + 255) / 256;   // 25000 (exact)
    k_agg1gemm2<<<nodeBlocks, 256, 0, stream>>>(rowstart, erow, h1, dinv,
                                                wf + 8192, wf + 8256, h2, N);

    k_agg2_csr<<<nodeBlocks, 256, 0, stream>>>(rowstart, erow, h2, dinv,
                                               wf + 10816, (float*)d_out, N);
}